// Round 1
// baseline (419.762 us; speedup 1.0000x reference)
//
#include <hip/hip_runtime.h>
#include <hip/hip_bf16.h>
#include <stdint.h>

// Problem constants
#define BB 8192
#define DD 1024
#define EE 8
#define HH 512
#define OO 1024

typedef __bf16 bf16_t;
typedef bf16_t bf16x8 __attribute__((ext_vector_type(8)));
typedef float f32x4 __attribute__((ext_vector_type(4)));
typedef uint32_t u32;

// ---------------- ws layout (bytes) ----------------
// imp[8] f32 @0, cnt[8] u32 @64,
// rowidx int[8][8192] @4096, rowgate f32[8][8192] @266240,
// xb bf16[8192][1024] @1MB, W1T bf16[8][512][1024] @17825792,
// W2T bf16[8][1024][512] @26214400. Total ~33MB (assumes ws_size >= 34MB).
#define WS_RIDX   4096
#define WS_RGATE  (4096 + EE*BB*4)
#define WS_XB     (1u<<20)
#define WS_W1T    (WS_XB + (size_t)BB*DD*2)
#define WS_W2T    (WS_W1T + (size_t)EE*HH*DD*2)

// ---------------------------------------------------------------------------
// Prep: W1 [E][D][H] fp32 -> W1T [E][H][D] bf16 ; W2 [E][H][O] -> W2T [E][O][H]
// 64x64 tiles through LDS. 2048 blocks x 256 threads.
// ---------------------------------------------------------------------------
__global__ __launch_bounds__(256) void k_prep(const float* __restrict__ W1,
                                              const float* __restrict__ W2,
                                              bf16_t* __restrict__ W1T,
                                              bf16_t* __restrict__ W2T) {
  __shared__ __align__(16) bf16_t t[64][72];  // +8 pad: 144B row stride
  int bid = blockIdx.x;
  const float* src; bf16_t* dst; int R, C; int tile;
  if (bid < 1024) {
    int e = bid >> 7; tile = bid & 127;
    src = W1 + (size_t)e * DD * HH; dst = W1T + (size_t)e * HH * DD;
    R = DD; C = HH;
  } else {
    bid -= 1024;
    int e = bid >> 7; tile = bid & 127;
    src = W2 + (size_t)e * HH * OO; dst = W2T + (size_t)e * OO * HH;
    R = HH; C = OO;
  }
  int tpc = C >> 6;
  int r0 = (tile / tpc) << 6, c0 = (tile % tpc) << 6;
  int tid = threadIdx.x;
  // load 64x64 fp32 coalesced, store transposed bf16 into LDS
  {
    int r = tid >> 2, cs = (tid & 3) << 4;
    const f32x4* sp = (const f32x4*)(src + (size_t)(r0 + r) * C + c0 + cs);
    #pragma unroll
    for (int q = 0; q < 4; ++q) {
      f32x4 v = sp[q];
      t[cs + q*4 + 0][r] = (bf16_t)v.x;
      t[cs + q*4 + 1][r] = (bf16_t)v.y;
      t[cs + q*4 + 2][r] = (bf16_t)v.z;
      t[cs + q*4 + 3][r] = (bf16_t)v.w;
    }
  }
  __syncthreads();
  // write out: row (c0+c) of dst, contiguous 16 bf16 per thread
  {
    int c = tid >> 2, rs = (tid & 3) << 4;
    bf16_t* op = dst + (size_t)(c0 + c) * R + r0 + rs;
    const uint4* lp = (const uint4*)(&t[c][rs]);
    uint4 a0 = lp[0], a1 = lp[1];
    ((uint4*)op)[0] = a0;
    ((uint4*)op)[1] = a1;
  }
}

// ---------------------------------------------------------------------------
// Gating: fp64-accumulated logits (top-2 selection must out-resolve fp32
// reference noise), full softmax for importance, top-2 softmax weights,
// per-expert row lists via atomics, x -> bf16. 1 wave per row.
// ---------------------------------------------------------------------------
__global__ __launch_bounds__(256) void k_gate(const float* __restrict__ x,
                                              const float* __restrict__ gW,
                                              const float* __restrict__ gb,
                                              float* __restrict__ imp,
                                              u32* __restrict__ cnt,
                                              int* __restrict__ ridx,
                                              float* __restrict__ rgate,
                                              bf16_t* __restrict__ xb) {
  __shared__ float s_imp[EE];
  int tid = threadIdx.x;
  if (tid < EE) s_imp[tid] = 0.f;
  __syncthreads();
  int lane = tid & 63, w = tid >> 6;
  int b = (blockIdx.x << 2) + w;
  double acc[EE];
  #pragma unroll
  for (int e = 0; e < EE; ++e) acc[e] = 0.0;
  const float* xrow = x + (size_t)b * DD;
  bf16_t* xbrow = xb + (size_t)b * DD;
  #pragma unroll
  for (int i = 0; i < 16; ++i) {
    int d = (i << 6) + lane;
    float xv = xrow[d];
    xbrow[d] = (bf16_t)xv;
    const f32x4* gp = (const f32x4*)(gW + (size_t)d * EE);
    f32x4 g0 = gp[0], g1 = gp[1];
    acc[0] += (double)xv * g0.x; acc[1] += (double)xv * g0.y;
    acc[2] += (double)xv * g0.z; acc[3] += (double)xv * g0.w;
    acc[4] += (double)xv * g1.x; acc[5] += (double)xv * g1.y;
    acc[6] += (double)xv * g1.z; acc[7] += (double)xv * g1.w;
  }
  #pragma unroll
  for (int e = 0; e < EE; ++e) {
    #pragma unroll
    for (int off = 32; off > 0; off >>= 1) acc[e] += __shfl_xor(acc[e], off);
  }
  if (lane == 0) {
    float v[EE];
    float m = -1e30f;
    #pragma unroll
    for (int e = 0; e < EE; ++e) { v[e] = (float)acc[e] + gb[e]; m = fmaxf(m, v[e]); }
    float s = 0.f, p[EE];
    #pragma unroll
    for (int e = 0; e < EE; ++e) { p[e] = expf(v[e] - m); s += p[e]; }
    float inv = 1.f / s;
    #pragma unroll
    for (int e = 0; e < EE; ++e) atomicAdd(&s_imp[e], p[e] * inv);
    // top-2 (strict > keeps lowest index on ties, matching lax.top_k)
    int i0 = 0; float b0 = v[0];
    #pragma unroll
    for (int e = 1; e < EE; ++e) if (v[e] > b0) { b0 = v[e]; i0 = e; }
    int i1 = -1; float b1v = -1e30f;
    #pragma unroll
    for (int e = 0; e < EE; ++e) if (e != i0 && v[e] > b1v) { b1v = v[e]; i1 = e; }
    float tt = expf(b1v - b0);
    float g0 = 1.f / (1.f + tt), g1 = tt / (1.f + tt);
    u32 p0 = atomicAdd(&cnt[i0], 1u);
    ridx[i0 * BB + p0] = b; rgate[i0 * BB + p0] = g0;
    u32 p1 = atomicAdd(&cnt[i1], 1u);
    ridx[i1 * BB + p1] = b; rgate[i1 * BB + p1] = g1;
  }
  __syncthreads();
  if (tid < EE) atomicAdd(&imp[tid], s_imp[tid]);
}

// ---------------------------------------------------------------------------
// Load-balance loss: 0.01 * E * sum((imp/B)^2)
// ---------------------------------------------------------------------------
__global__ void k_loss(const float* __restrict__ imp, float* __restrict__ outloss) {
  int tid = threadIdx.x;
  float v = (tid < EE) ? imp[tid] * (1.f / BB) : 0.f;
  v = v * v;
  #pragma unroll
  for (int off = 32; off > 0; off >>= 1) v += __shfl_xor(v, off);
  if (tid == 0) *outloss = 0.01f * (float)EE * v;
}

// ---------------------------------------------------------------------------
// Grouped MoE GEMM: block = 64 rows of one expert. Fused:
//   H = relu(X@W1[e]+b1), OUT += g * (H@W2[e]+b2) via fp32 atomics.
// expert = blockIdx&7 (XCD affinity: each expert's 2MB bf16 weights stay in
// one XCD's 4MB L2). 8 waves, MFMA 16x16x32 bf16, XOR-swizzled LDS (128KB):
//   sX   [64][64]   @elem 0      (stage A)
//   sW   [512][64]  @elem 32768  (W1T chunk in A, W2T half-chunk in B)
//   sH   [64][512]  @elem 0      (stage B; overwrites sX region after sync)
// swizzle: 16B block cb' = cb ^ (row&7)  -> conflict-free ds_read_b128.
// ---------------------------------------------------------------------------
#define SW_OFF 32768
__global__ __launch_bounds__(512, 2) void k_moe(const u32* __restrict__ cnt,
                                                const int* __restrict__ ridx,
                                                const float* __restrict__ rgate,
                                                const bf16_t* __restrict__ xb,
                                                const bf16_t* __restrict__ W1T,
                                                const bf16_t* __restrict__ W2T,
                                                const float* __restrict__ b1,
                                                const float* __restrict__ b2,
                                                float* __restrict__ out) {
  __shared__ __align__(16) bf16_t smem[65536];  // 128 KiB
  __shared__ int s_rb[64];
  __shared__ float s_rg[64];

  int e = blockIdx.x & 7, j = blockIdx.x >> 3;
  int n = (int)cnt[e];
  int r0 = j << 6;
  if (r0 >= n) return;
  int nr = min(64, n - r0);
  int tid = threadIdx.x;
  if (tid < 64) {
    int rr = r0 + tid;
    s_rb[tid] = (tid < nr) ? ridx[e * BB + rr] : 0;
    s_rg[tid] = (tid < nr) ? rgate[e * BB + rr] : 0.f;
  }
  __syncthreads();

  int lane = tid & 63, w = tid >> 6;
  int lr = lane & 15, lk = lane >> 4;

  // ---------------- Stage A: H = relu(X @ W1[e] + b1[e]) ----------------
  f32x4 acc[4][4];
  f32x4 zz = {0.f, 0.f, 0.f, 0.f};
  #pragma unroll
  for (int mm = 0; mm < 4; ++mm)
    #pragma unroll
    for (int nn = 0; nn < 4; ++nn) acc[mm][nn] = zz;

  const bf16_t* w1base = W1T + (size_t)e * HH * DD;
  for (int kk = 0; kk < 16; ++kk) {
    {  // stage X chunk (64x64): 512 threads, one 16B block each
      int r = tid >> 3, cb = tid & 7;
      uint4 v = *(const uint4*)(xb + (size_t)s_rb[r] * DD + (kk << 6) + (cb << 3));
      *(uint4*)(smem + (((r << 3) + (cb ^ (r & 7))) << 3)) = v;
    }
    {  // stage W1T chunk (512 h-rows x 64 d-cols)
      int r = tid >> 3, cb = tid & 7;
      const bf16_t* wsrc = w1base + (kk << 6);
      #pragma unroll
      for (int i = 0; i < 8; ++i) {
        int h = r + (i << 6);
        uint4 v = *(const uint4*)(wsrc + (size_t)h * DD + (cb << 3));
        *(uint4*)(smem + SW_OFF + (((h << 3) + (cb ^ (h & 7))) << 3)) = v;
      }
    }
    __syncthreads();
    #pragma unroll
    for (int ks = 0; ks < 2; ++ks) {
      int kcb = (ks << 2) + lk;  // 16B block index in chunk (0..7)
      bf16x8 af[4], bfr[4];
      #pragma unroll
      for (int mm = 0; mm < 4; ++mm) {
        int r = mm * 16 + lr;
        af[mm] = *(const bf16x8*)(smem + (((r << 3) + (kcb ^ (r & 7))) << 3));
      }
      #pragma unroll
      for (int nn = 0; nn < 4; ++nn) {
        int h = w * 64 + nn * 16 + lr;
        bfr[nn] = *(const bf16x8*)(smem + SW_OFF + (((h << 3) + (kcb ^ (h & 7))) << 3));
      }
      #pragma unroll
      for (int mm = 0; mm < 4; ++mm)
        #pragma unroll
        for (int nn = 0; nn < 4; ++nn)
          acc[mm][nn] = __builtin_amdgcn_mfma_f32_16x16x32_bf16(af[mm], bfr[nn], acc[mm][nn], 0, 0, 0);
    }
    __syncthreads();
  }

  // bias + relu, write H (bf16, swizzled) into smem[0..32768)
  {
    const float* b1p = b1 + (size_t)e * HH;
    #pragma unroll
    for (int nn = 0; nn < 4; ++nn) {
      int hcol = w * 64 + nn * 16 + lr;
      float bias = b1p[hcol];
      int cb = hcol >> 3, ci = hcol & 7;
      #pragma unroll
      for (int mm = 0; mm < 4; ++mm) {
        #pragma unroll
        for (int jj = 0; jj < 4; ++jj) {
          int r = mm * 16 + lk * 4 + jj;
          float hv = fmaxf(acc[mm][nn][jj] + bias, 0.f);
          smem[(((r << 6) + (cb ^ (r & 7))) << 3) + ci] = (bf16_t)hv;
        }
      }
    }
  }
  __syncthreads();

  // ---------------- Stage B: OUT += g * (H @ W2[e] + b2[e]) ----------------
  const bf16_t* w2base = W2T + (size_t)e * OO * HH;
  const float* b2p = b2 + (size_t)e * OO;
  #pragma unroll
  for (int nh = 0; nh < 2; ++nh) {
    f32x4 acc2[4][4];
    #pragma unroll
    for (int mm = 0; mm < 4; ++mm)
      #pragma unroll
      for (int nn = 0; nn < 4; ++nn) acc2[mm][nn] = zz;

    for (int k2 = 0; k2 < 8; ++k2) {
      {  // stage W2T half-chunk (512 o-rows x 64 h-cols)
        int r = tid >> 3, cb = tid & 7;
        const bf16_t* wsrc = w2base + (size_t)(nh * 512) * HH + (k2 << 6);
        #pragma unroll
        for (int i = 0; i < 8; ++i) {
          int o = r + (i << 6);
          uint4 v = *(const uint4*)(wsrc + (size_t)o * HH + (cb << 3));
          *(uint4*)(smem + SW_OFF + (((o << 3) + (cb ^ (o & 7))) << 3)) = v;
        }
      }
      __syncthreads();
      #pragma unroll
      for (int ks = 0; ks < 2; ++ks) {
        int kcb = (k2 << 3) + (ks << 2) + lk;  // H 16B-block col (0..63)
        int wcb = (ks << 2) + lk;              // within staged chunk (0..7)
        bf16x8 af[4], bfr[4];
        #pragma unroll
        for (int mm = 0; mm < 4; ++mm) {
          int r = mm * 16 + lr;
          af[mm] = *(const bf16x8*)(smem + (((r << 6) + (kcb ^ (r & 7))) << 3));
        }
        #pragma unroll
        for (int nn = 0; nn < 4; ++nn) {
          int o = w * 64 + nn * 16 + lr;  // local row within half
          bfr[nn] = *(const bf16x8*)(smem + SW_OFF + (((o << 3) + (wcb ^ (o & 7))) << 3));
        }
        #pragma unroll
        for (int mm = 0; mm < 4; ++mm)
          #pragma unroll
          for (int nn = 0; nn < 4; ++nn)
            acc2[mm][nn] = __builtin_amdgcn_mfma_f32_16x16x32_bf16(af[mm], bfr[nn], acc2[mm][nn], 0, 0, 0);
      }
      __syncthreads();
    }
    // epilogue: scatter-add weighted outputs
    #pragma unroll
    for (int nn = 0; nn < 4; ++nn) {
      int o = nh * 512 + w * 64 + nn * 16 + lr;
      float bias = b2p[o];
      #pragma unroll
      for (int mm = 0; mm < 4; ++mm) {
        #pragma unroll
        for (int jj = 0; jj < 4; ++jj) {
          int r = mm * 16 + lk * 4 + jj;
          if (r < nr) {
            float val = (acc2[mm][nn][jj] + bias) * s_rg[r];
            atomicAdd(out + (size_t)s_rb[r] * OO + o, val);
          }
        }
      }
    }
  }
}

// ---------------------------------------------------------------------------
extern "C" void kernel_launch(void* const* d_in, const int* in_sizes, int n_in,
                              void* d_out, int out_size, void* d_ws, size_t ws_size,
                              hipStream_t stream) {
  const float* x   = (const float*)d_in[0];
  const float* gW  = (const float*)d_in[1];
  const float* gb  = (const float*)d_in[2];
  const float* W1  = (const float*)d_in[3];
  const float* b1  = (const float*)d_in[4];
  const float* W2  = (const float*)d_in[5];
  const float* b2  = (const float*)d_in[6];
  float* out = (float*)d_out;

  uint8_t* ws = (uint8_t*)d_ws;
  float*   imp   = (float*)(ws + 0);
  u32*     cnt   = (u32*)(ws + 64);
  int*     ridx  = (int*)(ws + WS_RIDX);
  float*   rgate = (float*)(ws + WS_RGATE);
  bf16_t*  xb    = (bf16_t*)(ws + WS_XB);
  bf16_t*  W1T   = (bf16_t*)(ws + WS_W1T);
  bf16_t*  W2T   = (bf16_t*)(ws + WS_W2T);

  // zero output (atomicAdd target) + counters/importance
  hipMemsetAsync(d_out, 0, (size_t)((size_t)BB * OO + 1) * sizeof(float), stream);
  hipMemsetAsync(ws, 0, 128, stream);

  k_prep<<<2048, 256, 0, stream>>>(W1, W2, W1T, W2T);
  k_gate<<<BB / 4, 256, 0, stream>>>(x, gW, gb, imp, cnt, ridx, rgate, xb);
  k_loss<<<1, 64, 0, stream>>>(imp, out + (size_t)BB * OO);
  k_moe<<<EE * (BB / 64), 512, 0, stream>>>(cnt, ridx, rgate, xb, W1T, W2T, b1, b2, out);
}

// Round 2
// 257.804 us; speedup vs baseline: 1.6282x; 1.6282x over previous
//
#include <hip/hip_runtime.h>
#include <hip/hip_bf16.h>
#include <stdint.h>

// Problem constants
#define BB 8192
#define DD 1024
#define EE 8
#define HH 512
#define OO 1024

typedef __bf16 bf16_t;
typedef bf16_t bf16x8 __attribute__((ext_vector_type(8)));
typedef float f32x4 __attribute__((ext_vector_type(4)));
typedef uint32_t u32;

// Padded counter stride: 64B per counter -> no cache-line sharing
#define CSTRIDE 16

// ---------------- ws layout (bytes) ----------------
// imp[8] f32 (stride 16) @0 (512B), cnt[8] u32 (stride 16) @1024 (512B),
// rowidx int[8][8192] @4096, rowgate f32[8][8192] @266240,
// xb bf16[8192][1024] @1MB, W1T bf16[8][512][1024] @17825792,
// W2T bf16[8][1024][512] @26214400. Total ~33MB.
#define WS_CNT    1024
#define WS_RIDX   4096
#define WS_RGATE  (4096 + EE*BB*4)
#define WS_XB     (1u<<20)
#define WS_W1T    (WS_XB + (size_t)BB*DD*2)
#define WS_W2T    (WS_W1T + (size_t)EE*HH*DD*2)

// ---------------------------------------------------------------------------
// Prep: W1 [E][D][H] fp32 -> W1T [E][H][D] bf16 ; W2 [E][H][O] -> W2T [E][O][H]
// 64x64 tiles through LDS. 2048 blocks x 256 threads.
// ---------------------------------------------------------------------------
__global__ __launch_bounds__(256) void k_prep(const float* __restrict__ W1,
                                              const float* __restrict__ W2,
                                              bf16_t* __restrict__ W1T,
                                              bf16_t* __restrict__ W2T) {
  __shared__ __align__(16) bf16_t t[64][72];  // +8 pad: 144B row stride
  int bid = blockIdx.x;
  const float* src; bf16_t* dst; int R, C; int tile;
  if (bid < 1024) {
    int e = bid >> 7; tile = bid & 127;
    src = W1 + (size_t)e * DD * HH; dst = W1T + (size_t)e * HH * DD;
    R = DD; C = HH;
  } else {
    bid -= 1024;
    int e = bid >> 7; tile = bid & 127;
    src = W2 + (size_t)e * HH * OO; dst = W2T + (size_t)e * OO * HH;
    R = HH; C = OO;
  }
  int tpc = C >> 6;
  int r0 = (tile / tpc) << 6, c0 = (tile % tpc) << 6;
  int tid = threadIdx.x;
  {
    int r = tid >> 2, cs = (tid & 3) << 4;
    const f32x4* sp = (const f32x4*)(src + (size_t)(r0 + r) * C + c0 + cs);
    #pragma unroll
    for (int q = 0; q < 4; ++q) {
      f32x4 v = sp[q];
      t[cs + q*4 + 0][r] = (bf16_t)v.x;
      t[cs + q*4 + 1][r] = (bf16_t)v.y;
      t[cs + q*4 + 2][r] = (bf16_t)v.z;
      t[cs + q*4 + 3][r] = (bf16_t)v.w;
    }
  }
  __syncthreads();
  {
    int c = tid >> 2, rs = (tid & 3) << 4;
    bf16_t* op = dst + (size_t)(c0 + c) * R + r0 + rs;
    const uint4* lp = (const uint4*)(&t[c][rs]);
    uint4 a0 = lp[0], a1 = lp[1];
    ((uint4*)op)[0] = a0;
    ((uint4*)op)[1] = a1;
  }
}

// ---------------------------------------------------------------------------
// Gating, block-aggregated: 512 blocks x 4 waves; wave handles 4 rows.
// Per row: fp64-accumulated logits (top-2 must out-resolve fp32 ref noise),
// full softmax for importance, top-2 weights. Lists staged in LDS via LDS
// atomics; ONE global atomicAdd per (block,expert) on 64B-padded counters.
// Also emits x as bf16.
// ---------------------------------------------------------------------------
__global__ __launch_bounds__(256) void k_gate(const float* __restrict__ x,
                                              const float* __restrict__ gW,
                                              const float* __restrict__ gb,
                                              float* __restrict__ imp,
                                              u32* __restrict__ cnt,
                                              int* __restrict__ ridx,
                                              float* __restrict__ rgate,
                                              bf16_t* __restrict__ xb) {
  __shared__ float s_imp[EE];
  __shared__ u32 s_hist[EE];
  __shared__ u32 s_base[EE];
  __shared__ int   s_lb[EE][16];
  __shared__ float s_lg[EE][16];
  int tid = threadIdx.x;
  if (tid < EE) { s_imp[tid] = 0.f; s_hist[tid] = 0u; }
  __syncthreads();
  int lane = tid & 63, w = tid >> 6;

  float impl[EE];
  #pragma unroll
  for (int e = 0; e < EE; ++e) impl[e] = 0.f;

  #pragma unroll
  for (int r = 0; r < 4; ++r) {
    int b = (blockIdx.x << 4) + (w << 2) + r;
    const float* xrow = x + (size_t)b * DD;
    bf16_t* xbrow = xb + (size_t)b * DD;
    double acc[EE];
    #pragma unroll
    for (int e = 0; e < EE; ++e) acc[e] = 0.0;
    #pragma unroll
    for (int q = 0; q < 4; ++q) {
      int d0 = (q << 8) + (lane << 2);
      f32x4 xv = *(const f32x4*)(xrow + d0);
      bf16_t xc[4] = {(bf16_t)xv.x, (bf16_t)xv.y, (bf16_t)xv.z, (bf16_t)xv.w};
      *(uint2*)(xbrow + d0) = *(const uint2*)xc;
      #pragma unroll
      for (int j = 0; j < 4; ++j) {
        const f32x4* gp = (const f32x4*)(gW + (size_t)(d0 + j) * EE);
        f32x4 g0 = gp[0], g1 = gp[1];
        double xd = (double)xv[j];
        acc[0] += xd * g0.x; acc[1] += xd * g0.y;
        acc[2] += xd * g0.z; acc[3] += xd * g0.w;
        acc[4] += xd * g1.x; acc[5] += xd * g1.y;
        acc[6] += xd * g1.z; acc[7] += xd * g1.w;
      }
    }
    #pragma unroll
    for (int e = 0; e < EE; ++e) {
      #pragma unroll
      for (int off = 32; off > 0; off >>= 1) acc[e] += __shfl_xor(acc[e], off);
    }
    if (lane == 0) {
      float v[EE];
      float m = -1e30f;
      #pragma unroll
      for (int e = 0; e < EE; ++e) { v[e] = (float)acc[e] + gb[e]; m = fmaxf(m, v[e]); }
      float s = 0.f, p[EE];
      #pragma unroll
      for (int e = 0; e < EE; ++e) { p[e] = expf(v[e] - m); s += p[e]; }
      float inv = 1.f / s;
      #pragma unroll
      for (int e = 0; e < EE; ++e) impl[e] += p[e] * inv;
      // top-2 (strict > keeps lowest index on ties, matching lax.top_k)
      int i0 = 0; float b0 = v[0];
      #pragma unroll
      for (int e = 1; e < EE; ++e) if (v[e] > b0) { b0 = v[e]; i0 = e; }
      int i1 = -1; float b1v = -1e30f;
      #pragma unroll
      for (int e = 0; e < EE; ++e) if (e != i0 && v[e] > b1v) { b1v = v[e]; i1 = e; }
      float tt = expf(b1v - b0);
      float g0 = 1.f / (1.f + tt), g1 = tt / (1.f + tt);
      u32 p0 = atomicAdd(&s_hist[i0], 1u);
      s_lb[i0][p0] = b; s_lg[i0][p0] = g0;
      u32 p1 = atomicAdd(&s_hist[i1], 1u);
      s_lb[i1][p1] = b; s_lg[i1][p1] = g1;
    }
  }
  if (lane == 0) {
    #pragma unroll
    for (int e = 0; e < EE; ++e) atomicAdd(&s_imp[e], impl[e]);
  }
  __syncthreads();
  if (tid < EE) {
    s_base[tid] = atomicAdd(&cnt[tid * CSTRIDE], s_hist[tid]);
    atomicAdd(&imp[tid * CSTRIDE], s_imp[tid]);
  }
  __syncthreads();
  for (int s = tid; s < EE * 16; s += 256) {
    int e = s >> 4, k = s & 15;
    if ((u32)k < s_hist[e]) {
      u32 pos = s_base[e] + (u32)k;
      ridx[e * BB + pos] = s_lb[e][k];
      rgate[e * BB + pos] = s_lg[e][k];
    }
  }
}

// ---------------------------------------------------------------------------
// Load-balance loss: 0.01 * E * sum((imp/B)^2)
// ---------------------------------------------------------------------------
__global__ void k_loss(const float* __restrict__ imp, float* __restrict__ outloss) {
  int tid = threadIdx.x;
  float v = (tid < EE) ? imp[tid * CSTRIDE] * (1.f / BB) : 0.f;
  v = v * v;
  #pragma unroll
  for (int off = 32; off > 0; off >>= 1) v += __shfl_xor(v, off);
  if (tid == 0) *outloss = 0.01f * (float)EE * v;
}

// ---------------------------------------------------------------------------
// Grouped MoE GEMM: block = 64 rows of one expert. Fused:
//   H = relu(X@W1[e]+b1), OUT += g * (H@W2[e]+b2) via fp32 atomics.
// expert = blockIdx&7 (XCD affinity). 8 waves, MFMA 16x16x32 bf16,
// XOR-swizzled LDS (128KB). swizzle: 16B block cb' = cb ^ (row&7).
// ---------------------------------------------------------------------------
#define SW_OFF 32768
__global__ __launch_bounds__(512, 2) void k_moe(const u32* __restrict__ cnt,
                                                const int* __restrict__ ridx,
                                                const float* __restrict__ rgate,
                                                const bf16_t* __restrict__ xb,
                                                const bf16_t* __restrict__ W1T,
                                                const bf16_t* __restrict__ W2T,
                                                const float* __restrict__ b1,
                                                const float* __restrict__ b2,
                                                float* __restrict__ out) {
  __shared__ __align__(16) bf16_t smem[65536];  // 128 KiB
  __shared__ int s_rb[64];
  __shared__ float s_rg[64];

  int e = blockIdx.x & 7, j = blockIdx.x >> 3;
  int n = (int)cnt[e * CSTRIDE];
  int r0 = j << 6;
  if (r0 >= n) return;
  int nr = min(64, n - r0);
  int tid = threadIdx.x;
  if (tid < 64) {
    int rr = r0 + tid;
    s_rb[tid] = (tid < nr) ? ridx[e * BB + rr] : 0;
    s_rg[tid] = (tid < nr) ? rgate[e * BB + rr] : 0.f;
  }
  __syncthreads();

  int lane = tid & 63, w = tid >> 6;
  int lr = lane & 15, lk = lane >> 4;

  // ---------------- Stage A: H = relu(X @ W1[e] + b1[e]) ----------------
  f32x4 acc[4][4];
  f32x4 zz = {0.f, 0.f, 0.f, 0.f};
  #pragma unroll
  for (int mm = 0; mm < 4; ++mm)
    #pragma unroll
    for (int nn = 0; nn < 4; ++nn) acc[mm][nn] = zz;

  const bf16_t* w1base = W1T + (size_t)e * HH * DD;
  for (int kk = 0; kk < 16; ++kk) {
    {  // stage X chunk (64x64)
      int r = tid >> 3, cb = tid & 7;
      uint4 v = *(const uint4*)(xb + (size_t)s_rb[r] * DD + (kk << 6) + (cb << 3));
      *(uint4*)(smem + (((r << 3) + (cb ^ (r & 7))) << 3)) = v;
    }
    {  // stage W1T chunk (512 h-rows x 64 d-cols)
      int r = tid >> 3, cb = tid & 7;
      const bf16_t* wsrc = w1base + (kk << 6);
      #pragma unroll
      for (int i = 0; i < 8; ++i) {
        int h = r + (i << 6);
        uint4 v = *(const uint4*)(wsrc + (size_t)h * DD + (cb << 3));
        *(uint4*)(smem + SW_OFF + (((h << 3) + (cb ^ (h & 7))) << 3)) = v;
      }
    }
    __syncthreads();
    #pragma unroll
    for (int ks = 0; ks < 2; ++ks) {
      int kcb = (ks << 2) + lk;
      bf16x8 af[4], bfr[4];
      #pragma unroll
      for (int mm = 0; mm < 4; ++mm) {
        int r = mm * 16 + lr;
        af[mm] = *(const bf16x8*)(smem + (((r << 3) + (kcb ^ (r & 7))) << 3));
      }
      #pragma unroll
      for (int nn = 0; nn < 4; ++nn) {
        int h = w * 64 + nn * 16 + lr;
        bfr[nn] = *(const bf16x8*)(smem + SW_OFF + (((h << 3) + (kcb ^ (h & 7))) << 3));
      }
      #pragma unroll
      for (int mm = 0; mm < 4; ++mm)
        #pragma unroll
        for (int nn = 0; nn < 4; ++nn)
          acc[mm][nn] = __builtin_amdgcn_mfma_f32_16x16x32_bf16(af[mm], bfr[nn], acc[mm][nn], 0, 0, 0);
    }
    __syncthreads();
  }

  // bias + relu, write H (bf16, swizzled) into smem[0..32768)
  {
    const float* b1p = b1 + (size_t)e * HH;
    #pragma unroll
    for (int nn = 0; nn < 4; ++nn) {
      int hcol = w * 64 + nn * 16 + lr;
      float bias = b1p[hcol];
      int cb = hcol >> 3, ci = hcol & 7;
      #pragma unroll
      for (int mm = 0; mm < 4; ++mm) {
        #pragma unroll
        for (int jj = 0; jj < 4; ++jj) {
          int r = mm * 16 + lk * 4 + jj;
          float hv = fmaxf(acc[mm][nn][jj] + bias, 0.f);
          smem[(((r << 6) + (cb ^ (r & 7))) << 3) + ci] = (bf16_t)hv;
        }
      }
    }
  }
  __syncthreads();

  // ---------------- Stage B: OUT += g * (H @ W2[e] + b2[e]) ----------------
  const bf16_t* w2base = W2T + (size_t)e * OO * HH;
  const float* b2p = b2 + (size_t)e * OO;
  #pragma unroll
  for (int nh = 0; nh < 2; ++nh) {
    f32x4 acc2[4][4];
    #pragma unroll
    for (int mm = 0; mm < 4; ++mm)
      #pragma unroll
      for (int nn = 0; nn < 4; ++nn) acc2[mm][nn] = zz;

    for (int k2 = 0; k2 < 8; ++k2) {
      {  // stage W2T half-chunk (512 o-rows x 64 h-cols)
        int r = tid >> 3, cb = tid & 7;
        const bf16_t* wsrc = w2base + (size_t)(nh * 512) * HH + (k2 << 6);
        #pragma unroll
        for (int i = 0; i < 8; ++i) {
          int o = r + (i << 6);
          uint4 v = *(const uint4*)(wsrc + (size_t)o * HH + (cb << 3));
          *(uint4*)(smem + SW_OFF + (((o << 3) + (cb ^ (o & 7))) << 3)) = v;
        }
      }
      __syncthreads();
      #pragma unroll
      for (int ks = 0; ks < 2; ++ks) {
        int kcb = (k2 << 3) + (ks << 2) + lk;
        int wcb = (ks << 2) + lk;
        bf16x8 af[4], bfr[4];
        #pragma unroll
        for (int mm = 0; mm < 4; ++mm) {
          int r = mm * 16 + lr;
          af[mm] = *(const bf16x8*)(smem + (((r << 6) + (kcb ^ (r & 7))) << 3));
        }
        #pragma unroll
        for (int nn = 0; nn < 4; ++nn) {
          int o = w * 64 + nn * 16 + lr;
          bfr[nn] = *(const bf16x8*)(smem + SW_OFF + (((o << 3) + (wcb ^ (o & 7))) << 3));
        }
        #pragma unroll
        for (int mm = 0; mm < 4; ++mm)
          #pragma unroll
          for (int nn = 0; nn < 4; ++nn)
            acc2[mm][nn] = __builtin_amdgcn_mfma_f32_16x16x32_bf16(af[mm], bfr[nn], acc2[mm][nn], 0, 0, 0);
      }
      __syncthreads();
    }
    // epilogue: scatter-add weighted outputs
    #pragma unroll
    for (int nn = 0; nn < 4; ++nn) {
      int o = nh * 512 + w * 64 + nn * 16 + lr;
      float bias = b2p[o];
      #pragma unroll
      for (int mm = 0; mm < 4; ++mm) {
        #pragma unroll
        for (int jj = 0; jj < 4; ++jj) {
          int r = mm * 16 + lk * 4 + jj;
          if (r < nr) {
            float val = (acc2[mm][nn][jj] + bias) * s_rg[r];
            atomicAdd(out + (size_t)s_rb[r] * OO + o, val);
          }
        }
      }
    }
  }
}

// ---------------------------------------------------------------------------
extern "C" void kernel_launch(void* const* d_in, const int* in_sizes, int n_in,
                              void* d_out, int out_size, void* d_ws, size_t ws_size,
                              hipStream_t stream) {
  const float* x   = (const float*)d_in[0];
  const float* gW  = (const float*)d_in[1];
  const float* gb  = (const float*)d_in[2];
  const float* W1  = (const float*)d_in[3];
  const float* b1  = (const float*)d_in[4];
  const float* W2  = (const float*)d_in[5];
  const float* b2  = (const float*)d_in[6];
  float* out = (float*)d_out;

  uint8_t* ws = (uint8_t*)d_ws;
  float*   imp   = (float*)(ws + 0);
  u32*     cnt   = (u32*)(ws + WS_CNT);
  int*     ridx  = (int*)(ws + WS_RIDX);
  float*   rgate = (float*)(ws + WS_RGATE);
  bf16_t*  xb    = (bf16_t*)(ws + WS_XB);
  bf16_t*  W1T   = (bf16_t*)(ws + WS_W1T);
  bf16_t*  W2T   = (bf16_t*)(ws + WS_W2T);

  // zero output (atomicAdd target) + counters/importance
  hipMemsetAsync(d_out, 0, (size_t)((size_t)BB * OO + 1) * sizeof(float), stream);
  hipMemsetAsync(ws, 0, 2048, stream);

  k_prep<<<2048, 256, 0, stream>>>(W1, W2, W1T, W2T);
  k_gate<<<512, 256, 0, stream>>>(x, gW, gb, imp, cnt, ridx, rgate, xb);
  k_loss<<<1, 64, 0, stream>>>(imp, out + (size_t)BB * OO);
  k_moe<<<EE * (BB / 64), 512, 0, stream>>>(cnt, ridx, rgate, xb, W1T, W2T, b1, b2, out);
}